// Round 2
// baseline (314.800 us; speedup 1.0000x reference)
//
#include <hip/hip_runtime.h>
#include <stdint.h>

// Problem dims (fixed by reference setup_inputs)
#define B_DIM 4
#define S_DIM 4096
#define M_DIM (B_DIM * S_DIM)   // 16384 token rows
#define N_DIM 2048
#define K_DIM 2048

#define BM 128
#define BN 128
#define BK 64

typedef int v4i __attribute__((ext_vector_type(4)));

// ---------------------------------------------------------------------------
// Kernel 0: pack widened int32 weights -> int8 (harness passes ints as int32)
// ---------------------------------------------------------------------------
__global__ __launch_bounds__(256) void pack_w_kernel(const int* __restrict__ w32,
                                                     int8_t* __restrict__ w8) {
    const int i = (blockIdx.x * 256 + threadIdx.x) * 8;   // 8 elements/thread
    const int4 a = *reinterpret_cast<const int4*>(w32 + i);
    const int4 b = *reinterpret_cast<const int4*>(w32 + i + 4);
    uint32_t lo = (a.x & 255) | ((a.y & 255) << 8) | ((a.z & 255) << 16) | ((uint32_t)(a.w & 255) << 24);
    uint32_t hi = (b.x & 255) | ((b.y & 255) << 8) | ((b.z & 255) << 16) | ((uint32_t)(b.w & 255) << 24);
    int2 pk;
    pk.x = (int)lo;
    pk.y = (int)hi;
    *reinterpret_cast<int2*>(w8 + i) = pk;
}

// ---------------------------------------------------------------------------
// Kernel 1: per-token symmetric int8 quantization
// one 256-thread block per row; each thread handles 8 consecutive f32.
// ---------------------------------------------------------------------------
__global__ __launch_bounds__(256) void quant_kernel(const float* __restrict__ x,
                                                    int8_t* __restrict__ q,
                                                    float* __restrict__ a_s) {
    const int row = blockIdx.x;
    const int t = threadIdx.x;
    const int lane = t & 63;
    const int wid = t >> 6;

    const float* xr = x + (size_t)row * K_DIM;
    const float4* xv = reinterpret_cast<const float4*>(xr);
    float4 v0 = xv[t * 2 + 0];
    float4 v1 = xv[t * 2 + 1];

    float m = fmaxf(fmaxf(fmaxf(fabsf(v0.x), fabsf(v0.y)), fmaxf(fabsf(v0.z), fabsf(v0.w))),
                    fmaxf(fmaxf(fabsf(v1.x), fabsf(v1.y)), fmaxf(fabsf(v1.z), fabsf(v1.w))));

    // wave-64 butterfly reduce
    #pragma unroll
    for (int off = 32; off > 0; off >>= 1)
        m = fmaxf(m, __shfl_xor(m, off));

    __shared__ float wmax[4];
    if (lane == 0) wmax[wid] = m;
    __syncthreads();
    const float mag = fmaxf(fmaxf(wmax[0], wmax[1]), fmaxf(wmax[2], wmax[3]));

    // match reference exactly: scale = mag==0 ? 1 : mag/127 (IEEE div)
    const float scale = (mag == 0.0f) ? 1.0f : (mag / 127.0f);

    // q = round(clip(x/scale, -128, 127)), round-half-even via rintf
    float e[8] = {v0.x, v0.y, v0.z, v0.w, v1.x, v1.y, v1.z, v1.w};
    uint32_t lo = 0, hi = 0;
    #pragma unroll
    for (int j = 0; j < 4; ++j) {
        float d = e[j] / scale;
        d = fminf(fmaxf(d, -128.0f), 127.0f);
        int qi = (int)rintf(d);
        lo |= ((uint32_t)(qi & 255)) << (8 * j);
    }
    #pragma unroll
    for (int j = 0; j < 4; ++j) {
        float d = e[4 + j] / scale;
        d = fminf(fmaxf(d, -128.0f), 127.0f);
        int qi = (int)rintf(d);
        hi |= ((uint32_t)(qi & 255)) << (8 * j);
    }

    int2 pk;
    pk.x = (int)lo;
    pk.y = (int)hi;
    reinterpret_cast<int2*>(q + (size_t)row * K_DIM)[t] = pk;

    if (t == 0) a_s[row] = scale;
}

// ---------------------------------------------------------------------------
// Kernel 2: int8 GEMM  out[m][n] = (sum_k A[m][k]*W[n][k]) * a_s[m] * w_s[n]
// 128x128 tile, BK=64, 4 waves (each 64x64 quadrant = 4x4 mfma 16x16x64 frags)
// global_load_lds width-16 staging, linear LDS, 2-barrier K-loop (m97 pattern)
// ---------------------------------------------------------------------------
__global__ __launch_bounds__(256, 2) void gemm_i8_kernel(
    const int8_t* __restrict__ A,    // [M, K]
    const int8_t* __restrict__ W,    // [N, K]
    const float* __restrict__ a_s,   // [M]
    const float* __restrict__ w_s,   // [N]
    float* __restrict__ out)         // [M, N]
{
    __shared__ __attribute__((aligned(16))) int8_t As[BM * BK];
    __shared__ __attribute__((aligned(16))) int8_t Bs[BN * BK];

    const int t = threadIdx.x;
    const int lane = t & 63;
    const int wid = t >> 6;
    const int wr = wid >> 1;   // wave row quadrant (0..1)
    const int wc = wid & 1;    // wave col quadrant (0..1)

    // XCD-aware bijective swizzle (nwg=2048, divisible by 8)
    const int nwg = gridDim.x;
    const int cpx = nwg >> 3;
    const int bid = blockIdx.x;
    const int sbid = (bid & 7) * cpx + (bid >> 3);
    const int ntiles_n = N_DIM / BN;             // 16
    const int bm = sbid / ntiles_n;
    const int bn = sbid % ntiles_n;

    const int8_t* aPtr = A + (size_t)(bm * BM) * K_DIM;
    const int8_t* wPtr = W + (size_t)(bn * BN) * K_DIM;

    v4i acc[4][4] = {};

    const int frow = lane & 15;        // fragment row (A) / col row (B)
    const int fchunk = lane >> 4;      // which 16-byte K-chunk (0..3)

    for (int k0 = 0; k0 < K_DIM; k0 += BK) {
        // stage A tile (128x64 = 8 KB) and B tile via direct-to-LDS, 16B/lane
        #pragma unroll
        for (int i = 0; i < 2; ++i) {
            const int flat = i * 256 + t;
            const int row = flat >> 2;       // 0..127
            const int chunk = flat & 3;      // 0..3
            __builtin_amdgcn_global_load_lds(
                (const __attribute__((address_space(1))) void*)(aPtr + (size_t)row * K_DIM + k0 + chunk * 16),
                (__attribute__((address_space(3))) void*)(As + flat * 16),
                16, 0, 0);
            __builtin_amdgcn_global_load_lds(
                (const __attribute__((address_space(1))) void*)(wPtr + (size_t)row * K_DIM + k0 + chunk * 16),
                (__attribute__((address_space(3))) void*)(Bs + flat * 16),
                16, 0, 0);
        }
        __syncthreads();   // drains vmcnt before barrier (compiler-inserted)

        // each wave: 4x4 fragments of 16x16x64
        v4i afrag[4];
        v4i bfrag[4];
        #pragma unroll
        for (int mf = 0; mf < 4; ++mf) {
            const int r = wr * 64 + mf * 16 + frow;
            afrag[mf] = *(const v4i*)(As + r * BK + fchunk * 16);
        }
        #pragma unroll
        for (int nf = 0; nf < 4; ++nf) {
            const int r = wc * 64 + nf * 16 + frow;
            bfrag[nf] = *(const v4i*)(Bs + r * BK + fchunk * 16);
        }
        #pragma unroll
        for (int mf = 0; mf < 4; ++mf)
            #pragma unroll
            for (int nf = 0; nf < 4; ++nf)
                acc[mf][nf] = __builtin_amdgcn_mfma_i32_16x16x64_i8(
                    afrag[mf], bfrag[nf], acc[mf][nf], 0, 0, 0);

        __syncthreads();   // all reads done before next stage overwrites
    }

    // epilogue: dequant + store
    // C/D layout: col = lane&15, row = (lane>>4)*4 + j   [m89, dtype-independent]
    const int row0 = bm * BM + wr * 64;
    const int col0 = bn * BN + wc * 64;
    #pragma unroll
    for (int mf = 0; mf < 4; ++mf) {
        const int rbase = row0 + mf * 16 + (lane >> 4) * 4;
        #pragma unroll
        for (int nf = 0; nf < 4; ++nf) {
            const int c = col0 + nf * 16 + (lane & 15);
            const float ws = w_s[c];
            #pragma unroll
            for (int j = 0; j < 4; ++j) {
                const int r = rbase + j;
                const float o = ((float)acc[mf][nf][j] * a_s[r]) * ws;
                out[(size_t)r * N_DIM + c] = o;
            }
        }
    }
}

// ---------------------------------------------------------------------------
extern "C" void kernel_launch(void* const* d_in, const int* in_sizes, int n_in,
                              void* d_out, int out_size, void* d_ws, size_t ws_size,
                              hipStream_t stream) {
    const float* x = (const float*)d_in[0];
    const int* w32 = (const int*)d_in[1];       // int8 widened to int32 by harness
    const float* wscale = (const float*)d_in[2];
    float* out = (float*)d_out;

    // workspace layout: [ q int8 M*K | a_s f32 M | w8 int8 N*K ]
    int8_t* q = (int8_t*)d_ws;
    float* a_s = (float*)((char*)d_ws + (size_t)M_DIM * K_DIM);
    int8_t* w8 = (int8_t*)((char*)d_ws + (size_t)M_DIM * K_DIM + (size_t)M_DIM * 4);

    pack_w_kernel<<<(N_DIM * K_DIM) / (256 * 8), 256, 0, stream>>>(w32, w8);
    quant_kernel<<<M_DIM, 256, 0, stream>>>(x, q, a_s);

    const int grid = (M_DIM / BM) * (N_DIM / BN);   // 128 * 16 = 2048
    gemm_i8_kernel<<<grid, 256, 0, stream>>>(q, w8, a_s, wscale, out);
}

// Round 3
// 309.047 us; speedup vs baseline: 1.0186x; 1.0186x over previous
//
#include <hip/hip_runtime.h>
#include <stdint.h>

// Problem dims (fixed by reference setup_inputs)
#define M_DIM 16384
#define N_DIM 2048
#define K_DIM 2048

// GEMM geometry: 256x256 tile, BK=64 (i8), 8 waves (2M x 4N), 4-deep LDS pipe
#define BM 256
#define BN 256
#define BK 64
#define NT (K_DIM / BK)                  // 32 K-tiles
#define TILE_A_BYTES (BM * BK)           // 16384
#define TILE_B_BYTES (BN * BK)           // 16384
#define BUF_BYTES (TILE_A_BYTES + TILE_B_BYTES)   // 32768
#define SMEM_BYTES (4 * BUF_BYTES)       // 131072 (4-deep)

typedef int v4i __attribute__((ext_vector_type(4)));

// ---------------------------------------------------------------------------
// Kernel 0: pack widened int32 weights -> int8
// ---------------------------------------------------------------------------
__global__ __launch_bounds__(256) void pack_w_kernel(const int* __restrict__ w32,
                                                     int8_t* __restrict__ w8) {
    const int i = (blockIdx.x * 256 + threadIdx.x) * 8;
    const int4 a = *reinterpret_cast<const int4*>(w32 + i);
    const int4 b = *reinterpret_cast<const int4*>(w32 + i + 4);
    uint32_t lo = (a.x & 255) | ((a.y & 255) << 8) | ((a.z & 255) << 16) | ((uint32_t)(a.w & 255) << 24);
    uint32_t hi = (b.x & 255) | ((b.y & 255) << 8) | ((b.z & 255) << 16) | ((uint32_t)(b.w & 255) << 24);
    int2 pk;
    pk.x = (int)lo;
    pk.y = (int)hi;
    *reinterpret_cast<int2*>(w8 + i) = pk;
}

// ---------------------------------------------------------------------------
// Kernel 1: per-token symmetric int8 quantization.
// 1 divide/thread (inv = 127/mag) instead of 8 IEEE divides.
// ---------------------------------------------------------------------------
__global__ __launch_bounds__(256) void quant_kernel(const float* __restrict__ x,
                                                    int8_t* __restrict__ q,
                                                    float* __restrict__ a_s) {
    const int row = blockIdx.x;
    const int t = threadIdx.x;
    const int lane = t & 63;
    const int wid = t >> 6;

    const float4* xv = reinterpret_cast<const float4*>(x + (size_t)row * K_DIM);
    float4 v0 = xv[t * 2 + 0];
    float4 v1 = xv[t * 2 + 1];

    float m = fmaxf(fmaxf(fmaxf(fabsf(v0.x), fabsf(v0.y)), fmaxf(fabsf(v0.z), fabsf(v0.w))),
                    fmaxf(fmaxf(fabsf(v1.x), fabsf(v1.y)), fmaxf(fabsf(v1.z), fabsf(v1.w))));

    #pragma unroll
    for (int off = 32; off > 0; off >>= 1)
        m = fmaxf(m, __shfl_xor(m, off));

    __shared__ float wmax[4];
    if (lane == 0) wmax[wid] = m;
    __syncthreads();
    const float mag = fmaxf(fmaxf(wmax[0], wmax[1]), fmaxf(wmax[2], wmax[3]));

    const float inv = (mag == 0.0f) ? 1.0f : (127.0f / mag);

    float e[8] = {v0.x, v0.y, v0.z, v0.w, v1.x, v1.y, v1.z, v1.w};
    uint32_t lo = 0, hi = 0;
    #pragma unroll
    for (int j = 0; j < 4; ++j) {
        float d = e[j] * inv;
        d = fminf(fmaxf(d, -128.0f), 127.0f);
        int qi = (int)rintf(d);
        lo |= ((uint32_t)(qi & 255)) << (8 * j);
    }
    #pragma unroll
    for (int j = 0; j < 4; ++j) {
        float d = e[4 + j] * inv;
        d = fminf(fmaxf(d, -128.0f), 127.0f);
        int qi = (int)rintf(d);
        hi |= ((uint32_t)(qi & 255)) << (8 * j);
    }

    int2 pk;
    pk.x = (int)lo;
    pk.y = (int)hi;
    reinterpret_cast<int2*>(q + (size_t)row * K_DIM)[t] = pk;

    if (t == 0) a_s[row] = (mag == 0.0f) ? 1.0f : (mag / 127.0f);  // store exact ref scale
}

// ---------------------------------------------------------------------------
// Kernel 2: int8 GEMM, 256x256 tile, 4-deep counted-vmcnt pipeline.
//   - global_load_lds with PRE-SWIZZLED global source (linear LDS dest),
//     swizzle: chunk' = chunk ^ ((row>>1)&3) within each 64B row  -> 2-way
//     (free) bank aliasing on ds_read_b128 instead of 8-way.
//   - stage tile t+3 at top of iter t: its buffer (t-1 mod 4) was last read
//     in iter t-1, whose reads are drained before the iter t-1 end barrier.
//   - vmcnt(8) before each barrier: all but the 2 newest staged tiles have
//     landed => tile t+1 complete in LDS after the barrier. Never drains to 0.
// ---------------------------------------------------------------------------
__global__ __launch_bounds__(512, 2) void gemm_i8_kernel(
    const int8_t* __restrict__ A,    // [M, K]
    const int8_t* __restrict__ W,    // [N, K]
    const float* __restrict__ a_s,   // [M]
    const float* __restrict__ w_s,   // [N]
    float* __restrict__ out)         // [M, N]
{
    extern __shared__ int8_t smem[];

    const int t = threadIdx.x;
    const int lane = t & 63;
    const int wid = t >> 6;      // 0..7
    const int wr = wid >> 2;     // 0..1  (M half)
    const int wc = wid & 3;      // 0..3  (N quarter)

    // XCD-aware bijective swizzle (nwg = 512, divisible by 8)
    const int bid = blockIdx.x;
    const int sbid = (bid & 7) * (gridDim.x >> 3) + (bid >> 3);
    const int bm = sbid >> 3;    // 64 M-tiles
    const int bn = sbid & 7;     // 8 N-tiles

    const int8_t* aSrc = A + (size_t)(bm * BM) * K_DIM;
    const int8_t* bSrc = W + (size_t)(bn * BN) * K_DIM;

    // staging: tile = 256 rows x 64 B = 1024 x 16B chunks; thread covers f and f+512
    const int f0 = t, f1 = t + 512;
    const int r0 = f0 >> 2, u0 = f0 & 3;
    const int r1 = f1 >> 2, u1 = f1 & 3;
    const size_t gOff0 = (size_t)r0 * K_DIM + (size_t)((u0 ^ ((r0 >> 1) & 3)) << 4);
    const size_t gOff1 = (size_t)r1 * K_DIM + (size_t)((u1 ^ ((r1 >> 1) & 3)) << 4);

    #define STAGE(tile)                                                                     \
    do {                                                                                    \
        int8_t* base_ = smem + ((tile) & 3) * BUF_BYTES;                                    \
        const int k0_ = (tile) * BK;                                                        \
        __builtin_amdgcn_global_load_lds(                                                   \
            (const __attribute__((address_space(1))) void*)(aSrc + k0_ + gOff0),            \
            (__attribute__((address_space(3))) void*)(base_ + f0 * 16), 16, 0, 0);          \
        __builtin_amdgcn_global_load_lds(                                                   \
            (const __attribute__((address_space(1))) void*)(aSrc + k0_ + gOff1),            \
            (__attribute__((address_space(3))) void*)(base_ + f1 * 16), 16, 0, 0);          \
        __builtin_amdgcn_global_load_lds(                                                   \
            (const __attribute__((address_space(1))) void*)(bSrc + k0_ + gOff0),            \
            (__attribute__((address_space(3))) void*)(base_ + TILE_A_BYTES + f0 * 16), 16, 0, 0); \
        __builtin_amdgcn_global_load_lds(                                                   \
            (const __attribute__((address_space(1))) void*)(bSrc + k0_ + gOff1),            \
            (__attribute__((address_space(3))) void*)(base_ + TILE_A_BYTES + f1 * 16), 16, 0, 0); \
    } while (0)

    // fragment read addressing (swizzled): row base per lane, frag offset = idx*1024
    const int frow = lane & 15;
    const int fc = lane >> 4;                       // 16B k-chunk 0..3
    const int rA = wr * 128 + frow;                 // + mf*16
    const int rB = wc * 64 + frow;                  // + nf*16
    const int aOff = rA * 64 + ((((rA >> 1) & 3) ^ fc) << 4);   // mf*16 rows = +1024B, swz invariant
    const int bOff = rB * 64 + ((((rB >> 1) & 3) ^ fc) << 4);

    v4i acc[8][4] = {};

    STAGE(0);
    STAGE(1);
    STAGE(2);
    asm volatile("s_waitcnt vmcnt(8)" ::: "memory");   // tile 0 landed (per-wave)
    __builtin_amdgcn_s_barrier();
    asm volatile("" ::: "memory");

    for (int tt = 0; tt < NT; ++tt) {
        if (tt + 3 < NT) STAGE(tt + 3);

        const int8_t* Ab = smem + (tt & 3) * BUF_BYTES;
        const int8_t* Bb = Ab + TILE_A_BYTES;

        v4i af[8], bf[4];
        #pragma unroll
        for (int mf = 0; mf < 8; ++mf)
            af[mf] = *(const v4i*)(Ab + aOff + mf * 1024);
        #pragma unroll
        for (int nf = 0; nf < 4; ++nf)
            bf[nf] = *(const v4i*)(Bb + bOff + nf * 1024);

        __builtin_amdgcn_s_setprio(1);
        #pragma unroll
        for (int mf = 0; mf < 8; ++mf)
            #pragma unroll
            for (int nf = 0; nf < 4; ++nf)
                acc[mf][nf] = __builtin_amdgcn_mfma_i32_16x16x64_i8(
                    af[mf], bf[nf], acc[mf][nf], 0, 0, 0);
        __builtin_amdgcn_s_setprio(0);

        if (tt < NT - 1) {
            asm volatile("" ::: "memory");
            if (tt < NT - 3)        asm volatile("s_waitcnt vmcnt(8)" ::: "memory");
            else if (tt < NT - 2)   asm volatile("s_waitcnt vmcnt(4)" ::: "memory");
            else                    asm volatile("s_waitcnt vmcnt(0)" ::: "memory");
            __builtin_amdgcn_s_barrier();
            asm volatile("" ::: "memory");
        }
    }
    #undef STAGE

    // epilogue: dequant + store. C/D layout: col=lane&15, row=(lane>>4)*4+j [m89]
    const int row0 = bm * BM + wr * 128;
    const int col0 = bn * BN + wc * 64;
    #pragma unroll
    for (int mf = 0; mf < 8; ++mf) {
        const int rbase = row0 + mf * 16 + (lane >> 4) * 4;
        #pragma unroll
        for (int nf = 0; nf < 4; ++nf) {
            const int c = col0 + nf * 16 + (lane & 15);
            const float ws = w_s[c];
            #pragma unroll
            for (int j = 0; j < 4; ++j) {
                const int r = rbase + j;
                out[(size_t)r * N_DIM + c] = ((float)acc[mf][nf][j] * a_s[r]) * ws;
            }
        }
    }
}

// ---------------------------------------------------------------------------
extern "C" void kernel_launch(void* const* d_in, const int* in_sizes, int n_in,
                              void* d_out, int out_size, void* d_ws, size_t ws_size,
                              hipStream_t stream) {
    const float* x = (const float*)d_in[0];
    const int* w32 = (const int*)d_in[1];       // int8 widened to int32 by harness
    const float* wscale = (const float*)d_in[2];
    float* out = (float*)d_out;

    // workspace layout: [ q int8 M*K | a_s f32 M | w8 int8 N*K ]
    int8_t* q = (int8_t*)d_ws;
    float* a_s = (float*)((char*)d_ws + (size_t)M_DIM * K_DIM);
    int8_t* w8 = (int8_t*)((char*)d_ws + (size_t)M_DIM * K_DIM + (size_t)M_DIM * 4);

    static int smem_set = 0;
    if (!smem_set) {
        hipFuncSetAttribute(reinterpret_cast<const void*>(&gemm_i8_kernel),
                            hipFuncAttributeMaxDynamicSharedMemorySize, SMEM_BYTES);
        smem_set = 1;
    }

    pack_w_kernel<<<(N_DIM * K_DIM) / (256 * 8), 256, 0, stream>>>(w32, w8);
    quant_kernel<<<M_DIM, 256, 0, stream>>>(x, q, a_s);

    const int grid = (M_DIM / BM) * (N_DIM / BN);   // 64 * 8 = 512
    gemm_i8_kernel<<<grid, 512, SMEM_BYTES, stream>>>(q, w8, a_s, wscale, out);
}